// Round 1
// baseline (441.041 us; speedup 1.0000x reference)
//
#include <hip/hip_runtime.h>
#include <hip/hip_bf16.h>
#include <math.h>

// Problem constants (from reference)
#define D_BINS 59
#define CTX    80
#define O_TOT  139      // D_BINS + CTX
#define K_CIN  256
#define PIXELS 704      // 16*44
#define BNPAIR 24       // B*N = 4*6
#define BEVHW  16384    // 128*128
#define NBATCH 4

// Workspace layout (floats):
//   xdepth : [BNPAIR][D_BINS][PIXELS]      = 996,864 floats
//   ctx    : [BNPAIR][PIXELS][CTX]         = 1,351,680 floats
//   bevtmp : [NBATCH][BEVHW][CTX]          = 5,242,880 floats
#define XDEPTH_OFF 0
#define XDEPTH_SZ  (BNPAIR * D_BINS * PIXELS)
#define CTX_OFF    (XDEPTH_OFF + XDEPTH_SZ)
#define CTX_SZ     (BNPAIR * PIXELS * CTX)
#define BEV_OFF    (CTX_OFF + CTX_SZ)
#define BEV_SZ     (NBATCH * BEVHW * CTX)

// ---------------------------------------------------------------------------
// Kernel 1: per-(b,n) GEMM  x[o][pix] = sum_k w[o][k]*img[k][pix] + bias[o]
// Tile: 16 outputs x 128 pixels, K-step 16. Block = 256 threads (16x16),
// each thread computes 8 pixels (stride-16 within the tile -> conflict-free
// LDS reads and coalesced epilogue stores).
// Depth part (o<59) -> xdepth[(bn*59+o)*704+pix]
// Context part      -> ctx[(bn*704+pix)*80 + (o-59)]   (transposed!)
// ---------------------------------------------------------------------------
__global__ __launch_bounds__(256) void gemm_kernel(
    const float* __restrict__ img,    // (BNPAIR, 256, 704)
    const float* __restrict__ w,      // (139, 256)
    const float* __restrict__ bias,   // (139)
    float* __restrict__ xdepth,
    float* __restrict__ ctx)
{
    __shared__ float As[16][17];   // +1 pad
    __shared__ float Bs[16][128];

    const int tid = threadIdx.x;
    const int tx  = tid & 15;      // pixel-group lane
    const int ty  = tid >> 4;      // output row
    const int bn  = blockIdx.z;
    const int o0  = blockIdx.y * 16;
    const int p0  = blockIdx.x * 128;

    const float* imgbn = img + (size_t)bn * K_CIN * PIXELS;

    float acc[8];
#pragma unroll
    for (int p = 0; p < 8; ++p) acc[p] = 0.f;

    for (int kt = 0; kt < K_CIN; kt += 16) {
        // A tile (16x16): coalesced over tx
        {
            int o = o0 + ty;
            As[ty][tx] = (o < O_TOT) ? w[o * K_CIN + kt + tx] : 0.f;
        }
        // B tile (16 x 128): 2048 elems, 8 per thread, coalesced over pix
#pragma unroll
        for (int r = 0; r < 8; ++r) {
            int e  = tid + 256 * r;
            int kl = e >> 7;        // 0..15
            int p  = e & 127;
            int pg = p0 + p;
            Bs[kl][p] = (pg < PIXELS) ? imgbn[(kt + kl) * PIXELS + pg] : 0.f;
        }
        __syncthreads();

#pragma unroll
        for (int kk = 0; kk < 16; ++kk) {
            float a = As[ty][kk];
#pragma unroll
            for (int p = 0; p < 8; ++p)
                acc[p] += a * Bs[kk][p * 16 + tx];
        }
        __syncthreads();
    }

    const int o = o0 + ty;
    if (o < O_TOT) {
        const float bv = bias[o];
        if (o < D_BINS) {
            float* dst = xdepth + ((size_t)bn * D_BINS + o) * PIXELS;
#pragma unroll
            for (int p = 0; p < 8; ++p) {
                int pg = p0 + p * 16 + tx;
                if (pg < PIXELS) dst[pg] = acc[p] + bv;
            }
        } else {
            const int c = o - D_BINS;
            float* dst = ctx + ((size_t)bn * PIXELS) * CTX + c;
#pragma unroll
            for (int p = 0; p < 8; ++p) {
                int pg = p0 + p * 16 + tx;
                if (pg < PIXELS) dst[(size_t)pg * CTX] = acc[p] + bv;
            }
        }
    }
}

// ---------------------------------------------------------------------------
// Kernel 2: softmax over the 59 depth bins, in place. One wave per pixel,
// 4 waves per block. Lane d holds bin d (d<59), shuffle reductions.
// ---------------------------------------------------------------------------
__global__ __launch_bounds__(256) void softmax_kernel(float* __restrict__ xdepth)
{
    const int pix  = blockIdx.x * 4 + (threadIdx.x >> 6);
    const int lane = threadIdx.x & 63;
    if (pix >= BNPAIR * PIXELS) return;
    const int bn = pix / PIXELS;
    const int pp = pix - bn * PIXELS;

    float* base = xdepth + (size_t)bn * D_BINS * PIXELS + pp;
    float v = (lane < D_BINS) ? base[(size_t)lane * PIXELS] : -INFINITY;

    float m = v;
#pragma unroll
    for (int off = 32; off; off >>= 1) m = fmaxf(m, __shfl_xor(m, off, 64));
    float e = (lane < D_BINS) ? __expf(v - m) : 0.f;
    float s = e;
#pragma unroll
    for (int off = 32; off; off >>= 1) s += __shfl_xor(s, off, 64);
    if (lane < D_BINS) base[(size_t)lane * PIXELS] = e / s;
}

// ---------------------------------------------------------------------------
// Kernel 3: scatter. One thread per (point, channel). point = (bn*59+d)*704+pp
// depth  = xdepth[point]                      (broadcast across 80 lanes)
// ctxv   = ctx[(bn*704+pp)*80 + c]            (coalesced)
// target = bevtmp[(b*16384 + g0*128+g1)*80+c] (80 consecutive floats / point)
// ---------------------------------------------------------------------------
__global__ __launch_bounds__(256) void scatter_kernel(
    const float* __restrict__ xdepth,
    const float* __restrict__ ctx,
    const int*   __restrict__ geom,   // (point, 2)
    float*       __restrict__ bevtmp)
{
    const int idx   = blockIdx.x * 256 + threadIdx.x;   // < 79,749,120
    const int point = idx / CTX;
    const int c     = idx - point * CTX;

    const int bnd = point / PIXELS;        // bn*59 + d
    const int pp  = point - bnd * PIXELS;
    const int bn  = bnd / D_BINS;
    const int b   = bn / 6;

    const float dep  = xdepth[point];
    const int   g0   = geom[2 * (size_t)point];
    const int   g1   = geom[2 * (size_t)point + 1];
    const int   cell = g0 * 128 + g1;
    const float cv   = ctx[((size_t)bn * PIXELS + pp) * CTX + c];

    atomicAdd(&bevtmp[((size_t)b * BEVHW + cell) * CTX + c], dep * cv);
}

// ---------------------------------------------------------------------------
// Kernel 4: transpose (b, cell, c) -> (b, c, cell) into d_out.
// Writes coalesced; reads stride-320B (L2-resident, 21 MB).
// ---------------------------------------------------------------------------
__global__ __launch_bounds__(256) void transpose_kernel(
    const float* __restrict__ bevtmp, float* __restrict__ out)
{
    const int gid = blockIdx.x * 256 + threadIdx.x;  // < 5,242,880
    const int b    = gid / (CTX * BEVHW);
    const int rem  = gid - b * (CTX * BEVHW);
    const int c    = rem >> 14;          // /16384
    const int cell = rem & (BEVHW - 1);
    out[gid] = bevtmp[((size_t)b * BEVHW + cell) * CTX + c];
}

extern "C" void kernel_launch(void* const* d_in, const int* in_sizes, int n_in,
                              void* d_out, int out_size, void* d_ws, size_t ws_size,
                              hipStream_t stream)
{
    const float* img   = (const float*)d_in[0];
    const float* w     = (const float*)d_in[4];
    const float* bias  = (const float*)d_in[5];
    const int*   geom  = (const int*)d_in[6];
    float*       out   = (float*)d_out;

    float* ws     = (float*)d_ws;
    float* xdepth = ws + XDEPTH_OFF;
    float* ctx    = ws + CTX_OFF;
    float* bevtmp = ws + BEV_OFF;

    // Zero the BEV accumulator (workspace is poisoned 0xAA each call).
    hipMemsetAsync(bevtmp, 0, (size_t)BEV_SZ * sizeof(float), stream);

    // 1. GEMM + bias, split into depth logits / transposed context
    {
        dim3 grid(6, 9, BNPAIR);   // 6 pixel-tiles(128), 9 o-tiles(16), 24 bn
        gemm_kernel<<<grid, 256, 0, stream>>>(img, w, bias, xdepth, ctx);
    }
    // 2. softmax over depth bins (16896 pixels, 4 per block)
    softmax_kernel<<<(BNPAIR * PIXELS) / 4, 256, 0, stream>>>(xdepth);

    // 3. scatter-accumulate: 996,864 points x 80 channels
    {
        const int total = BNPAIR * D_BINS * PIXELS * CTX;  // 79,749,120
        scatter_kernel<<<total / 256, 256, 0, stream>>>(xdepth, ctx, geom, bevtmp);
    }
    // 4. transpose to (B, C, H, W)
    transpose_kernel<<<out_size / 256, 256, 0, stream>>>(bevtmp, out);
}

// Round 2
// 346.402 us; speedup vs baseline: 1.2732x; 1.2732x over previous
//
#include <hip/hip_runtime.h>
#include <hip/hip_bf16.h>
#include <math.h>

// Problem constants (from reference)
#define D_BINS 59
#define CTX    80
#define O_TOT  139      // D_BINS + CTX
#define K_CIN  256
#define PIXELS 704      // 16*44
#define BNPAIR 24       // B*N = 4*6
#define BEVHW  16384    // 128*128
#define NBATCH 4
#define NPOINT (BNPAIR * D_BINS * PIXELS)   // 996,864
#define NCELL  (NBATCH * BEVHW)             // 65,536

// Workspace layout (float/int units, all offsets even -> 8B aligned):
//   xdepth  : [BNPAIR][D_BINS][PIXELS]  996,864 f
//   ctx     : [BNPAIR][PIXELS][CTX]   1,351,680 f
//   counts  : [NCELL]                    65,536 i
//   offs    : [NCELL]                    65,536 i
//   fill    : [NCELL]                    65,536 i
//   blocksum: [256] i ; blockoff: [256] i
//   plist   : [NPOINT] uint2          1,993,728 u32
#define XDEPTH_OFF 0
#define CTX_OFF    (XDEPTH_OFF + NPOINT)
#define COUNTS_OFF (CTX_OFF + BNPAIR * PIXELS * CTX)
#define OFFS_OFF   (COUNTS_OFF + NCELL)
#define FILL_OFF   (OFFS_OFF + NCELL)
#define BSUM_OFF   (FILL_OFF + NCELL)
#define BOFF_OFF   (BSUM_OFF + 256)
#define PLIST_OFF  (BOFF_OFF + 256)

// ---------------------------------------------------------------------------
// Kernel 1: per-(b,n) GEMM  x[o][pix] = sum_k w[o][k]*img[k][pix] + bias[o]
// Tile: 64 outputs x 128 pixels, K-step 16. Block = 256 threads; each thread
// computes a 4x8 register micro-tile (o = o0+ty*4+i, p = p0+tx*8+j) so the
// inner loop is 3 ds_read_b128 per 32 FMAs.
// Depth (o<59)  -> xdepth[(bn*59+o)*704+pix]
// Context       -> ctx[(bn*704+pix)*80 + (o-59)]   (transposed)
// ---------------------------------------------------------------------------
__global__ __launch_bounds__(256) void gemm_kernel(
    const float* __restrict__ img,    // (BNPAIR, 256, 704)
    const float* __restrict__ w,      // (139, 256)
    const float* __restrict__ bias,   // (139)
    float* __restrict__ xdepth,
    float* __restrict__ ctx)
{
    __shared__ float As[16][64];    // [k][o_local]
    __shared__ float Bs[16][128];   // [k][p_local]

    const int tid = threadIdx.x;
    const int tx  = tid & 15;
    const int ty  = tid >> 4;
    const int bn  = blockIdx.z;
    const int o0  = blockIdx.y * 64;
    const int p0  = blockIdx.x * 128;

    const float* imgbn = img + (size_t)bn * K_CIN * PIXELS;

    float acc[4][8];
#pragma unroll
    for (int i = 0; i < 4; ++i)
#pragma unroll
        for (int j = 0; j < 8; ++j) acc[i][j] = 0.f;

    const int a_ol = tid >> 2;          // 0..63
    const int a_kc = (tid & 3) * 4;     // 0,4,8,12

    for (int kt = 0; kt < K_CIN; kt += 16) {
        // A tile: 64 o x 16 k, one float4 per thread (k-contiguous in w)
        {
            int o = o0 + a_ol;
            float4 v = make_float4(0.f, 0.f, 0.f, 0.f);
            if (o < O_TOT) v = *(const float4*)&w[(size_t)o * K_CIN + kt + a_kc];
            As[a_kc + 0][a_ol] = v.x;
            As[a_kc + 1][a_ol] = v.y;
            As[a_kc + 2][a_ol] = v.z;
            As[a_kc + 3][a_ol] = v.w;
        }
        // B tile: 16 k x 128 p, two float4 per thread, coalesced over pixels
#pragma unroll
        for (int r = 0; r < 2; ++r) {
            int e   = tid + 256 * r;
            int k_l = e >> 5;           // 0..15
            int p4  = (e & 31) * 4;     // 0..124
            int pg  = p0 + p4;
            float4 v = make_float4(0.f, 0.f, 0.f, 0.f);
            if (pg < PIXELS) v = *(const float4*)&imgbn[(size_t)(kt + k_l) * PIXELS + pg];
            *(float4*)&Bs[k_l][p4] = v;
        }
        __syncthreads();

#pragma unroll
        for (int kk = 0; kk < 16; ++kk) {
            float4 a  = *(const float4*)&As[kk][ty * 4];
            float4 b0 = *(const float4*)&Bs[kk][tx * 8];
            float4 b1 = *(const float4*)&Bs[kk][tx * 8 + 4];
            const float av[4] = {a.x, a.y, a.z, a.w};
            const float bv[8] = {b0.x, b0.y, b0.z, b0.w, b1.x, b1.y, b1.z, b1.w};
#pragma unroll
            for (int i = 0; i < 4; ++i)
#pragma unroll
                for (int j = 0; j < 8; ++j)
                    acc[i][j] += av[i] * bv[j];
        }
        __syncthreads();
    }

    const bool full_p = (p0 + 127) < PIXELS;
#pragma unroll
    for (int i = 0; i < 4; ++i) {
        const int o = o0 + ty * 4 + i;
        if (o >= O_TOT) continue;
        const float bv = bias[o];
        if (o < D_BINS) {
            float* dst = xdepth + ((size_t)bn * D_BINS + o) * PIXELS + p0 + tx * 8;
            if (full_p) {
#pragma unroll
                for (int j = 0; j < 8; ++j) dst[j] = acc[i][j] + bv;
            } else {
#pragma unroll
                for (int j = 0; j < 8; ++j) {
                    if (p0 + tx * 8 + j < PIXELS) dst[j] = acc[i][j] + bv;
                }
            }
        } else {
            const int c = o - D_BINS;
            float* dst = ctx + ((size_t)bn * PIXELS + p0 + tx * 8) * CTX + c;
#pragma unroll
            for (int j = 0; j < 8; ++j) {
                if (full_p || (p0 + tx * 8 + j < PIXELS)) dst[(size_t)j * CTX] = acc[i][j] + bv;
            }
        }
    }
}

// ---------------------------------------------------------------------------
// Kernel 2: softmax over 59 depth bins, in place. One wave per pixel.
// ---------------------------------------------------------------------------
__global__ __launch_bounds__(256) void softmax_kernel(float* __restrict__ xdepth)
{
    const int pix  = blockIdx.x * 4 + (threadIdx.x >> 6);
    const int lane = threadIdx.x & 63;
    if (pix >= BNPAIR * PIXELS) return;
    const int bn = pix / PIXELS;
    const int pp = pix - bn * PIXELS;

    float* base = xdepth + (size_t)bn * D_BINS * PIXELS + pp;
    float v = (lane < D_BINS) ? base[(size_t)lane * PIXELS] : -INFINITY;

    float m = v;
#pragma unroll
    for (int off = 32; off; off >>= 1) m = fmaxf(m, __shfl_xor(m, off, 64));
    float e = (lane < D_BINS) ? __expf(v - m) : 0.f;
    float s = e;
#pragma unroll
    for (int off = 32; off; off >>= 1) s += __shfl_xor(s, off, 64);
    if (lane < D_BINS) base[(size_t)lane * PIXELS] = e / s;
}

// ---------------------------------------------------------------------------
// Binning: count, scan(3), fill
// ---------------------------------------------------------------------------
__global__ __launch_bounds__(256) void count_kernel(
    const int* __restrict__ geom, int* __restrict__ counts)
{
    const int pt = blockIdx.x * 256 + threadIdx.x;        // < NPOINT exactly
    const int g0 = geom[2 * (size_t)pt];
    const int g1 = geom[2 * (size_t)pt + 1];
    const int bn = pt / (D_BINS * PIXELS);
    const int b  = bn / 6;
    atomicAdd(&counts[b * BEVHW + g0 * 128 + g1], 1);
}

__global__ __launch_bounds__(256) void scan1_kernel(
    const int* __restrict__ counts, int* __restrict__ offs, int* __restrict__ blocksum)
{
    __shared__ int s[256];
    const int tid = threadIdx.x;
    const int gid = blockIdx.x * 256 + tid;
    const int v   = counts[gid];
    s[tid] = v;
    __syncthreads();
#pragma unroll
    for (int off = 1; off < 256; off <<= 1) {
        int t = (tid >= off) ? s[tid - off] : 0;
        __syncthreads();
        s[tid] += t;
        __syncthreads();
    }
    offs[gid] = s[tid] - v;               // exclusive within block
    if (tid == 255) blocksum[blockIdx.x] = s[255];
}

__global__ __launch_bounds__(256) void scan2_kernel(
    const int* __restrict__ blocksum, int* __restrict__ blockoff)
{
    __shared__ int s[256];
    const int tid = threadIdx.x;
    const int v   = blocksum[tid];
    s[tid] = v;
    __syncthreads();
#pragma unroll
    for (int off = 1; off < 256; off <<= 1) {
        int t = (tid >= off) ? s[tid - off] : 0;
        __syncthreads();
        s[tid] += t;
        __syncthreads();
    }
    blockoff[tid] = s[tid] - v;
}

__global__ __launch_bounds__(256) void scan3_kernel(
    int* __restrict__ offs, const int* __restrict__ blockoff, int* __restrict__ fill)
{
    const int gid = blockIdx.x * 256 + threadIdx.x;
    const int v   = offs[gid] + blockoff[blockIdx.x];
    offs[gid] = v;
    fill[gid] = v;
}

__global__ __launch_bounds__(256) void fill_kernel(
    const int*   __restrict__ geom,
    const float* __restrict__ xdepth,
    int*         __restrict__ fill,
    uint2*       __restrict__ plist)
{
    const int pt  = blockIdx.x * 256 + threadIdx.x;       // < NPOINT exactly
    const int g0  = geom[2 * (size_t)pt];
    const int g1  = geom[2 * (size_t)pt + 1];
    const int bnd = pt / PIXELS;          // bn*59 + d
    const int pp  = pt - bnd * PIXELS;
    const int bn  = bnd / D_BINS;
    const int b   = bn / 6;
    const float dep = xdepth[pt];
    const int pos = atomicAdd(&fill[b * BEVHW + g0 * 128 + g1], 1);
    plist[pos] = make_uint2(__float_as_uint(dep), (bn * PIXELS + pp) * CTX);
}

// ---------------------------------------------------------------------------
// Gather: one wave per (b, cell). Lane c accumulates channel c (and c+64 for
// c<16). Per point: one broadcast 8B list read + coalesced 320B ctx read.
// Writes d_out directly in (B, C, H, W) layout.
// ---------------------------------------------------------------------------
__global__ __launch_bounds__(256) void gather_kernel(
    const uint2* __restrict__ plist,
    const int*   __restrict__ offs,
    const int*   __restrict__ counts,
    const float* __restrict__ ctx,
    float*       __restrict__ out)
{
    const int wid  = blockIdx.x * 4 + (threadIdx.x >> 6);   // bcell < NCELL
    const int lane = threadIdx.x & 63;
    const int start = offs[wid];
    const int cnt   = counts[wid];

    float a0 = 0.f, a1 = 0.f;
    for (int i = 0; i < cnt; ++i) {
        const uint2 pe = plist[start + i];
        const float dep = __uint_as_float(pe.x);
        const float* cb = ctx + pe.y;
        a0 += dep * cb[lane];
        if (lane < 16) a1 += dep * cb[64 + lane];
    }
    const int b    = wid >> 14;
    const int cell = wid & (BEVHW - 1);
    out[((size_t)(b * CTX + lane)) * BEVHW + cell] = a0;
    if (lane < 16)
        out[((size_t)(b * CTX + 64 + lane)) * BEVHW + cell] = a1;
}

extern "C" void kernel_launch(void* const* d_in, const int* in_sizes, int n_in,
                              void* d_out, int out_size, void* d_ws, size_t ws_size,
                              hipStream_t stream)
{
    const float* img  = (const float*)d_in[0];
    const float* w    = (const float*)d_in[4];
    const float* bias = (const float*)d_in[5];
    const int*   geom = (const int*)d_in[6];
    float*       out  = (float*)d_out;

    float* ws     = (float*)d_ws;
    float* xdepth = ws + XDEPTH_OFF;
    float* ctx    = ws + CTX_OFF;
    int*   counts = (int*)(ws + COUNTS_OFF);
    int*   offs   = (int*)(ws + OFFS_OFF);
    int*   fill   = (int*)(ws + FILL_OFF);
    int*   bsum   = (int*)(ws + BSUM_OFF);
    int*   boff   = (int*)(ws + BOFF_OFF);
    uint2* plist  = (uint2*)(ws + PLIST_OFF);

    // counters must start at zero (ws is poisoned 0xAA each call)
    hipMemsetAsync(counts, 0, NCELL * sizeof(int), stream);

    // 1. GEMM + bias -> depth logits (bn,d,pix) / transposed context (bn,pix,c)
    {
        dim3 grid(6, 3, BNPAIR);   // 6 pixel-tiles(128), 3 o-tiles(64), 24 bn
        gemm_kernel<<<grid, 256, 0, stream>>>(img, w, bias, xdepth, ctx);
    }
    // 2. softmax over depth bins
    softmax_kernel<<<(BNPAIR * PIXELS) / 4, 256, 0, stream>>>(xdepth);

    // 3. counting sort by BEV cell
    count_kernel<<<NPOINT / 256, 256, 0, stream>>>(geom, counts);
    scan1_kernel<<<NCELL / 256, 256, 0, stream>>>(counts, offs, bsum);
    scan2_kernel<<<1, 256, 0, stream>>>(bsum, boff);
    scan3_kernel<<<NCELL / 256, 256, 0, stream>>>(offs, boff, fill);
    fill_kernel<<<NPOINT / 256, 256, 0, stream>>>(geom, xdepth, fill, plist);

    // 4. gather per (b,cell), write (B,C,H,W) directly
    gather_kernel<<<NCELL / 4, 256, 0, stream>>>(plist, offs, counts, ctx, out);
}

// Round 3
// 296.210 us; speedup vs baseline: 1.4889x; 1.1694x over previous
//
#include <hip/hip_runtime.h>
#include <hip/hip_bf16.h>
#include <math.h>

// Problem constants (from reference)
#define D_BINS 59
#define CTX    80
#define O_TOT  139      // D_BINS + CTX
#define K_CIN  256
#define PIXELS 704      // 16*44
#define BNPAIR 24       // B*N = 4*6
#define BEVHW  16384    // 128*128
#define NBATCH 4
#define NPOINT (BNPAIR * D_BINS * PIXELS)   // 996,864
#define NCELL  (NBATCH * BEVHW)             // 65,536
#define GCELLS 16       // cells per gather block (16 waves x 64 lanes = 1024)

// Workspace layout (float/int units, all offsets even -> 8B aligned):
#define XDEPTH_OFF 0
#define CTX_OFF    (XDEPTH_OFF + NPOINT)
#define COUNTS_OFF (CTX_OFF + BNPAIR * PIXELS * CTX)
#define OFFS_OFF   (COUNTS_OFF + NCELL)
#define FILL_OFF   (OFFS_OFF + NCELL)
#define BSUM_OFF   (FILL_OFF + NCELL)
#define BOFF_OFF   (BSUM_OFF + 256)
#define PLIST_OFF  (BOFF_OFF + 256)

// ---------------------------------------------------------------------------
// Kernel 1: per-(b,n) GEMM  x[o][pix] = sum_k w[o][k]*img[k][pix] + bias[o]
// 64 outputs x 128 pixels tile, K-step 16, 4x8 register micro-tile.
// Depth (o<59)  -> xdepth[(bn*59+o)*704+pix]
// Context       -> ctx[(bn*704+pix)*80 + (o-59)]   (transposed)
// ---------------------------------------------------------------------------
__global__ __launch_bounds__(256) void gemm_kernel(
    const float* __restrict__ img,    // (BNPAIR, 256, 704)
    const float* __restrict__ w,      // (139, 256)
    const float* __restrict__ bias,   // (139)
    float* __restrict__ xdepth,
    float* __restrict__ ctx)
{
    __shared__ float As[16][64];    // [k][o_local]
    __shared__ float Bs[16][128];   // [k][p_local]

    const int tid = threadIdx.x;
    const int tx  = tid & 15;
    const int ty  = tid >> 4;
    const int bn  = blockIdx.z;
    const int o0  = blockIdx.y * 64;
    const int p0  = blockIdx.x * 128;

    const float* imgbn = img + (size_t)bn * K_CIN * PIXELS;

    float acc[4][8];
#pragma unroll
    for (int i = 0; i < 4; ++i)
#pragma unroll
        for (int j = 0; j < 8; ++j) acc[i][j] = 0.f;

    const int a_ol = tid >> 2;          // 0..63
    const int a_kc = (tid & 3) * 4;     // 0,4,8,12

    for (int kt = 0; kt < K_CIN; kt += 16) {
        // A tile: 64 o x 16 k, one float4 per thread (k-contiguous in w)
        {
            int o = o0 + a_ol;
            float4 v = make_float4(0.f, 0.f, 0.f, 0.f);
            if (o < O_TOT) v = *(const float4*)&w[(size_t)o * K_CIN + kt + a_kc];
            As[a_kc + 0][a_ol] = v.x;
            As[a_kc + 1][a_ol] = v.y;
            As[a_kc + 2][a_ol] = v.z;
            As[a_kc + 3][a_ol] = v.w;
        }
        // B tile: 16 k x 128 p, two float4 per thread, coalesced over pixels
#pragma unroll
        for (int r = 0; r < 2; ++r) {
            int e   = tid + 256 * r;
            int k_l = e >> 5;           // 0..15
            int p4  = (e & 31) * 4;     // 0..124
            int pg  = p0 + p4;
            float4 v = make_float4(0.f, 0.f, 0.f, 0.f);
            if (pg < PIXELS) v = *(const float4*)&imgbn[(size_t)(kt + k_l) * PIXELS + pg];
            *(float4*)&Bs[k_l][p4] = v;
        }
        __syncthreads();

#pragma unroll
        for (int kk = 0; kk < 16; ++kk) {
            float4 a  = *(const float4*)&As[kk][ty * 4];
            float4 b0 = *(const float4*)&Bs[kk][tx * 8];
            float4 b1 = *(const float4*)&Bs[kk][tx * 8 + 4];
            const float av[4] = {a.x, a.y, a.z, a.w};
            const float bv[8] = {b0.x, b0.y, b0.z, b0.w, b1.x, b1.y, b1.z, b1.w};
#pragma unroll
            for (int i = 0; i < 4; ++i)
#pragma unroll
                for (int j = 0; j < 8; ++j)
                    acc[i][j] += av[i] * bv[j];
        }
        __syncthreads();
    }

    const bool full_p = (p0 + 127) < PIXELS;
#pragma unroll
    for (int i = 0; i < 4; ++i) {
        const int o = o0 + ty * 4 + i;
        if (o >= O_TOT) continue;
        const float bv = bias[o];
        if (o < D_BINS) {
            float* dst = xdepth + ((size_t)bn * D_BINS + o) * PIXELS + p0 + tx * 8;
#pragma unroll
            for (int j = 0; j < 8; ++j) {
                if (full_p || (p0 + tx * 8 + j < PIXELS)) dst[j] = acc[i][j] + bv;
            }
        } else {
            const int c = o - D_BINS;
            float* dst = ctx + ((size_t)bn * PIXELS + p0 + tx * 8) * CTX + c;
#pragma unroll
            for (int j = 0; j < 8; ++j) {
                if (full_p || (p0 + tx * 8 + j < PIXELS)) dst[(size_t)j * CTX] = acc[i][j] + bv;
            }
        }
    }
}

// ---------------------------------------------------------------------------
// Kernel 2: softmax over 59 depth bins, in place. ONE THREAD PER PIXEL:
// consecutive threads -> consecutive pixels -> every load/store coalesced.
// 59 values live in registers.
// ---------------------------------------------------------------------------
__global__ __launch_bounds__(256) void softmax_kernel(float* __restrict__ xdepth)
{
    const int pix = blockIdx.x * 256 + threadIdx.x;   // < 16896 exactly
    const int bn  = pix / PIXELS;
    const int pp  = pix - bn * PIXELS;
    float* base = xdepth + ((size_t)bn * D_BINS) * PIXELS + pp;

    float v[D_BINS];
    float m = -INFINITY;
#pragma unroll
    for (int d = 0; d < D_BINS; ++d) {
        v[d] = base[(size_t)d * PIXELS];
        m = fmaxf(m, v[d]);
    }
    float s = 0.f;
#pragma unroll
    for (int d = 0; d < D_BINS; ++d) {
        v[d] = __expf(v[d] - m);
        s += v[d];
    }
    const float inv = 1.f / s;
#pragma unroll
    for (int d = 0; d < D_BINS; ++d)
        base[(size_t)d * PIXELS] = v[d] * inv;
}

// ---------------------------------------------------------------------------
// Binning: count, scan(3), fill
// ---------------------------------------------------------------------------
__global__ __launch_bounds__(256) void count_kernel(
    const int* __restrict__ geom, int* __restrict__ counts)
{
    const int pt = blockIdx.x * 256 + threadIdx.x;        // < NPOINT exactly
    const int g0 = geom[2 * (size_t)pt];
    const int g1 = geom[2 * (size_t)pt + 1];
    const int bn = pt / (D_BINS * PIXELS);
    const int b  = bn / 6;
    atomicAdd(&counts[b * BEVHW + g0 * 128 + g1], 1);
}

__global__ __launch_bounds__(256) void scan1_kernel(
    const int* __restrict__ counts, int* __restrict__ offs, int* __restrict__ blocksum)
{
    __shared__ int s[256];
    const int tid = threadIdx.x;
    const int gid = blockIdx.x * 256 + tid;
    const int v   = counts[gid];
    s[tid] = v;
    __syncthreads();
#pragma unroll
    for (int off = 1; off < 256; off <<= 1) {
        int t = (tid >= off) ? s[tid - off] : 0;
        __syncthreads();
        s[tid] += t;
        __syncthreads();
    }
    offs[gid] = s[tid] - v;               // exclusive within block
    if (tid == 255) blocksum[blockIdx.x] = s[255];
}

__global__ __launch_bounds__(256) void scan2_kernel(
    const int* __restrict__ blocksum, int* __restrict__ blockoff)
{
    __shared__ int s[256];
    const int tid = threadIdx.x;
    const int v   = blocksum[tid];
    s[tid] = v;
    __syncthreads();
#pragma unroll
    for (int off = 1; off < 256; off <<= 1) {
        int t = (tid >= off) ? s[tid - off] : 0;
        __syncthreads();
        s[tid] += t;
        __syncthreads();
    }
    blockoff[tid] = s[tid] - v;
}

__global__ __launch_bounds__(256) void scan3_kernel(
    int* __restrict__ offs, const int* __restrict__ blockoff, int* __restrict__ fill)
{
    const int gid = blockIdx.x * 256 + threadIdx.x;
    const int v   = offs[gid] + blockoff[blockIdx.x];
    offs[gid] = v;
    fill[gid] = v;
}

__global__ __launch_bounds__(256) void fill_kernel(
    const int*   __restrict__ geom,
    const float* __restrict__ xdepth,
    int*         __restrict__ fill,
    uint2*       __restrict__ plist)
{
    const int pt  = blockIdx.x * 256 + threadIdx.x;       // < NPOINT exactly
    const int g0  = geom[2 * (size_t)pt];
    const int g1  = geom[2 * (size_t)pt + 1];
    const int bnd = pt / PIXELS;          // bn*59 + d
    const int pp  = pt - bnd * PIXELS;
    const int bn  = bnd / D_BINS;
    const int b   = bn / 6;
    const float dep = xdepth[pt];
    const int pos = atomicAdd(&fill[b * BEVHW + g0 * 128 + g1], 1);
    plist[pos] = make_uint2(__float_as_uint(dep), (bn * PIXELS + pp) * CTX);
}

// ---------------------------------------------------------------------------
// Gather: 1024-thread block = 16 waves = 16 consecutive (b,cell)s.
// Per wave: 2-point-per-iteration loop (two independent load chains).
// Results staged in LDS, then written as full 64B cachelines per channel row.
// ---------------------------------------------------------------------------
__global__ __launch_bounds__(1024) void gather_kernel(
    const uint2* __restrict__ plist,
    const int*   __restrict__ offs,
    const int*   __restrict__ counts,
    const float* __restrict__ ctx,
    float*       __restrict__ out)
{
    __shared__ float sacc[CTX][GCELLS + 1];   // +1 pad: conflict-free writes

    const int wv   = threadIdx.x >> 6;                  // 0..15 (cell within block)
    const int lane = threadIdx.x & 63;
    const int wid  = blockIdx.x * GCELLS + wv;          // (b,cell)
    const int start = offs[wid];
    const int cnt   = counts[wid];

    float a0 = 0.f, a1 = 0.f;
    int i = 0;
    for (; i + 1 < cnt; i += 2) {
        const uint2 p0 = plist[start + i];
        const uint2 p1 = plist[start + i + 1];
        const float d0 = __uint_as_float(p0.x);
        const float d1 = __uint_as_float(p1.x);
        const float* c0 = ctx + p0.y;
        const float* c1 = ctx + p1.y;
        const float v0 = c0[lane];
        const float v1 = c1[lane];
        a0 += d0 * v0;
        a0 += d1 * v1;
        if (lane < 16) {
            a1 += d0 * c0[64 + lane];
            a1 += d1 * c1[64 + lane];
        }
    }
    if (i < cnt) {
        const uint2 pe = plist[start + i];
        const float dep = __uint_as_float(pe.x);
        const float* cb = ctx + pe.y;
        a0 += dep * cb[lane];
        if (lane < 16) a1 += dep * cb[64 + lane];
    }

    sacc[lane][wv] = a0;
    if (lane < 16) sacc[64 + lane][wv] = a1;
    __syncthreads();

    // Write phase: thread t -> channel c = t/16, cell-offset cl = t%16.
    // Each group of 16 consecutive threads writes one 64B contiguous run.
    const int c0 = threadIdx.x >> 4;        // 0..63
    const int cl = threadIdx.x & 15;
    const int widbase  = blockIdx.x * GCELLS;
    const int b        = widbase >> 14;
    const int cellbase = widbase & (BEVHW - 1);
#pragma unroll
    for (int cc = c0; cc < CTX; cc += 64)
        out[((size_t)(b * CTX + cc)) * BEVHW + cellbase + cl] = sacc[cc][cl];
}

extern "C" void kernel_launch(void* const* d_in, const int* in_sizes, int n_in,
                              void* d_out, int out_size, void* d_ws, size_t ws_size,
                              hipStream_t stream)
{
    const float* img  = (const float*)d_in[0];
    const float* w    = (const float*)d_in[4];
    const float* bias = (const float*)d_in[5];
    const int*   geom = (const int*)d_in[6];
    float*       out  = (float*)d_out;

    float* ws     = (float*)d_ws;
    float* xdepth = ws + XDEPTH_OFF;
    float* ctx    = ws + CTX_OFF;
    int*   counts = (int*)(ws + COUNTS_OFF);
    int*   offs   = (int*)(ws + OFFS_OFF);
    int*   fill   = (int*)(ws + FILL_OFF);
    int*   bsum   = (int*)(ws + BSUM_OFF);
    int*   boff   = (int*)(ws + BOFF_OFF);
    uint2* plist  = (uint2*)(ws + PLIST_OFF);

    // counters must start at zero (ws is poisoned 0xAA each call)
    hipMemsetAsync(counts, 0, NCELL * sizeof(int), stream);

    // 1. GEMM + bias -> depth logits (bn,d,pix) / transposed context (bn,pix,c)
    {
        dim3 grid(6, 3, BNPAIR);   // 6 pixel-tiles(128), 3 o-tiles(64), 24 bn
        gemm_kernel<<<grid, 256, 0, stream>>>(img, w, bias, xdepth, ctx);
    }
    // 2. softmax over depth bins (coalesced, thread-per-pixel)
    softmax_kernel<<<(BNPAIR * PIXELS) / 256, 256, 0, stream>>>(xdepth);

    // 3. counting sort by BEV cell
    count_kernel<<<NPOINT / 256, 256, 0, stream>>>(geom, counts);
    scan1_kernel<<<NCELL / 256, 256, 0, stream>>>(counts, offs, bsum);
    scan2_kernel<<<1, 256, 0, stream>>>(bsum, boff);
    scan3_kernel<<<NCELL / 256, 256, 0, stream>>>(offs, boff, fill);
    fill_kernel<<<NPOINT / 256, 256, 0, stream>>>(geom, xdepth, fill, plist);

    // 4. gather per (b,cell), LDS-staged coalesced writes to (B,C,H,W)
    gather_kernel<<<NCELL / GCELLS, 1024, 0, stream>>>(plist, offs, counts, ctx, out);
}